// Round 6
// baseline (3130.913 us; speedup 1.0000x reference)
//
#include <hip/hip_runtime.h>

static constexpr int kN = 50000;    // nodes
static constexpr int kE = 800000;   // edges
static constexpr int kH = 64;       // hidden
static constexpr int kG = 256;      // graphs (pool segments)
static constexpr int kC = 250;      // classes
static constexpr int kNH = kN * kH;
static constexpr float kEps = 1e-5f;
static constexpr float kNeg = 0.2f;

// ---- device-global scratch (allocated at module load; rewritten every call) ----
__device__ float g_F0[kNH];
__device__ float g_F1[kNH];
__device__ float g_XL[kNH];
__device__ float g_XR[kNH];
__device__ float g_ACC[kNH];
__device__ float g_LOG[kE];
__device__ unsigned g_MX[kN];
__device__ float g_DEN[kN];
__device__ float g_SUMS[128];
__device__ unsigned g_POOL[kG * kH];   // 16384
__device__ float g_Z[kG * 256];        // 65536
__device__ float g_HSUMS[512];         // head BN stats (256 sum + 256 sumsq)

// ---- monotonic float<->uint encoding for atomicMax on floats ----
__device__ inline unsigned fenc(float f) {
  unsigned u = __float_as_uint(f);
  return (u & 0x80000000u) ? ~u : (u | 0x80000000u);
}
__device__ inline float fdec(unsigned u) {
  return (u & 0x80000000u) ? __uint_as_float(u & 0x7FFFFFFFu)
                           : __uint_as_float(~u);
}

// ---- start-of-call zeroing: SUMS, POOL, HSUMS ----
__global__ void GCN_41781441855659_kernel() {
  int i = blockIdx.x * 256 + threadIdx.x;
  int stride = gridDim.x * 256;
  for (int k = i; k < kG * kH; k += stride) g_POOL[k] = 0u;
  for (int k = i; k < 512; k += stride) g_HSUMS[k] = 0.0f;
  for (int k = i; k < 128; k += stride) g_SUMS[k] = 0.0f;
}

// ---- per-conv zeroing: MX, DEN, SUMS ----
__global__ void k_zero_conv() {
  int i = blockIdx.x * 256 + threadIdx.x;
  int stride = gridDim.x * 256;
  for (int k = i; k < kN; k += stride) {
    g_MX[k] = 0u;
    g_DEN[k] = 0.0f;
  }
  if (blockIdx.x == 0 && threadIdx.x < 128) g_SUMS[threadIdx.x] = 0.0f;
}

// ---- zero the aggregation buffer ----
__global__ void k_zero_acc() {
  int i = blockIdx.x * 256 + threadIdx.x;
  int stride = gridDim.x * 256;
  for (int k = i; k < kNH; k += stride) g_ACC[k] = 0.0f;
}

// ---- dual GEMM: g_XL = X*Wl^T + bl ; g_XR = X*Wr^T + br ----
// sel: 0 -> Xext, 1 -> g_F0, 2 -> g_F1.
__global__ void k_gemm_dual(int sel, const float* Xext, const float* Wl,
                            const float* bl, const float* Wr,
                            const float* br) {
  const float* X = (sel == 0) ? Xext : (sel == 1 ? g_F0 : g_F1);
  __shared__ float wl[64][64];
  __shared__ float wr[64][64];
  for (int i = threadIdx.x; i < 4096; i += 256) {
    int c = i >> 6, k = i & 63;
    wl[k][c] = Wl[i];  // transposed store: wl[k][c] = Wl[c][k]
    wr[k][c] = Wr[i];
  }
  __syncthreads();
  int lane = threadIdx.x & 63;
  int w = threadIdx.x >> 6;
  int r0 = blockIdx.x * 64;
  for (int rl = w; rl < 64; rl += 4) {
    int r = r0 + rl;
    if (r >= kN) break;
    const float* xrow = X + (size_t)r * kH;
    float accl = bl[lane];
    float accr = br[lane];
#pragma unroll
    for (int k = 0; k < 64; k++) {
      float xv = xrow[k];
      accl += xv * wl[k][lane];
      accr += xv * wr[k][lane];
    }
    g_XL[(size_t)r * 64 + lane] = accl;
    g_XR[(size_t)r * 64 + lane] = accr;
  }
}

// ---- edge pass 1: logits + segment max (wave per edge) ----
__global__ void k_edge_logits(const int* src, const int* dst, const float* ea,
                              const float* We, const float* att) {
  int e = blockIdx.x * 4 + (threadIdx.x >> 6);
  int lane = threadIdx.x & 63;
  int s = src[e], d = dst[e];
  float w0 = We[lane * 2 + 0], w1 = We[lane * 2 + 1];
  float ea0 = ea[e * 2 + 0], ea1 = ea[e * 2 + 1];
  float m = g_XL[(size_t)s * 64 + lane] + g_XR[(size_t)d * 64 + lane] +
            ea0 * w0 + ea1 * w1;
  m = (m >= 0.0f) ? m : kNeg * m;
  float t = m * att[lane];
#pragma unroll
  for (int off = 32; off; off >>= 1) t += __shfl_xor(t, off);
  if (lane == 0) {
    g_LOG[e] = t;
    atomicMax(&g_MX[d], fenc(t));
  }
}

// ---- edge pass 2: exp + denom (thread per edge); LOG overwritten ----
__global__ void k_edge_softmax(const int* dst) {
  int e = blockIdx.x * 256 + threadIdx.x;
  int d = dst[e];
  float ex = expf(g_LOG[e] - fdec(g_MX[d]));
  g_LOG[e] = ex;
  atomicAdd(&g_DEN[d], ex);
}

// ---- edge pass 3: alpha * xl[src] scatter-add (wave per edge) ----
__global__ void k_edge_aggr(const int* src, const int* dst) {
  int e = blockIdx.x * 4 + (threadIdx.x >> 6);
  int lane = threadIdx.x & 63;
  int s = src[e], d = dst[e];
  float alpha = g_LOG[e] / g_DEN[d];
  atomicAdd(&g_ACC[(size_t)d * 64 + lane],
            alpha * g_XL[(size_t)s * 64 + lane]);
}

// ---- BN stats: per-channel sum & sumsq. sel: 1 -> g_XL, 2 -> g_ACC ----
__global__ void k_bn_stats(int sel) {
  const float* x = (sel == 1) ? g_XL : g_ACC;
  int c = threadIdx.x & 63;
  int sub = threadIdx.x >> 6;
  float s = 0.0f, ss = 0.0f;
  for (int r = blockIdx.x * 4 + sub; r < kN; r += gridDim.x * 4) {
    float v = x[(size_t)r * 64 + c];
    s += v;
    ss += v * v;
  }
  __shared__ float ls[4][64];
  __shared__ float lss[4][64];
  ls[sub][c] = s;
  lss[sub][c] = ss;
  __syncthreads();
  if (threadIdx.x < 64) {
    float t = ls[0][c] + ls[1][c] + ls[2][c] + ls[3][c];
    float tt = lss[0][c] + lss[1][c] + lss[2][c] + lss[3][c];
    atomicAdd(&g_SUMS[c], t);
    atomicAdd(&g_SUMS[64 + c], tt);
  }
}

// ---- BN apply + optional residual + PReLU ----
// sel_in: 1->g_XL, 2->g_ACC.  use_res: add g_F0.  sel_out: 1->g_F0, 2->g_F1.
__global__ void k_bn_apply(int sel_in, int use_res, int sel_out,
                           const float* g, const float* beta,
                           const float* pa) {
  const float* x = (sel_in == 1) ? g_XL : g_ACC;
  float* out = (sel_out == 1) ? g_F0 : g_F1;
  const float inv = 1.0f / (float)kN;
  float a = pa[0];
  for (int idx = blockIdx.x * 256 + threadIdx.x; idx < kNH;
       idx += gridDim.x * 256) {
    int c = idx & 63;
    float mean = g_SUMS[c] * inv;
    float var = g_SUMS[64 + c] * inv - mean * mean;
    float sc = g[c] * rsqrtf(var + kEps);
    float sh = beta[c] - mean * sc;
    float v = x[idx] * sc + sh;
    if (use_res) v += g_F0[idx];
    out[idx] = (v >= 0.0f) ? v : a * v;
  }
}

// ---- segment max pool: wave per row, atomicMax into POOL[g*64+lane] ----
__global__ void k_pool_max(const int* batch) {
  int r = blockIdx.x * 4 + (threadIdx.x >> 6);
  int lane = threadIdx.x & 63;
  if (r >= kN) return;
  int g = batch[r];
  float v = g_F0[(size_t)r * 64 + lane];
  atomicMax(&g_POOL[g * 64 + lane], fenc(v));
}

// ---- head stage 1: Z[g][j] = b1[j] + pooled[g] . W1[j]; BN stats over G ----
__global__ void k_head_gemm1(const float* W1, const float* b1) {
  int g = blockIdx.x;   // 256 graphs
  int j = threadIdx.x;  // 256 output cols
  __shared__ float p[64];
  if (j < 64) p[j] = fdec(g_POOL[g * 64 + j]);
  __syncthreads();
  float y = b1[j];
  const float* wrow = W1 + (size_t)j * 64;
#pragma unroll
  for (int k = 0; k < 64; k++) y += p[k] * wrow[k];
  g_Z[(size_t)g * 256 + j] = y;
  atomicAdd(&g_HSUMS[j], y);
  atomicAdd(&g_HSUMS[256 + j], y * y);
}

// ---- head stage 2: BN -> PReLU -> out = z @ W2^T + b2 ----
__global__ void k_head_out(const float* g1, const float* beta1,
                           const float* pa, const float* W2, const float* b2,
                           float* out) {
  int g = blockIdx.x;   // 256 graphs
  int j = threadIdx.x;  // 256 threads
  __shared__ float zs[256];
  {
    const float inv = 1.0f / (float)kG;
    float mean = g_HSUMS[j] * inv;
    float var = g_HSUMS[256 + j] * inv - mean * mean;
    float sc = g1[j] * rsqrtf(var + kEps);
    float a = pa[0];
    float z = (g_Z[(size_t)g * 256 + j] - mean) * sc + beta1[j];
    zs[j] = (z >= 0.0f) ? z : a * z;
  }
  __syncthreads();
  if (j < kC) {
    const float* wrow = W2 + (size_t)j * 256;
    float acc = b2[j];
#pragma unroll 8
    for (int k = 0; k < 256; k++) acc += zs[k] * wrow[k];
    out[(size_t)g * kC + j] = acc;
  }
}

extern "C" void kernel_launch(void* const* d_in, const int* in_sizes, int n_in,
                              void* d_out, int out_size, void* d_ws,
                              size_t ws_size, hipStream_t stream) {
  const float* x = (const float*)d_in[0];
  const int* ei = (const int*)d_in[1];
  const int* src = ei;
  const int* dst = ei + kE;
  const float* ea = (const float*)d_in[2];
  const int* batch = (const int*)d_in[3];
  const float* pre_W = (const float*)d_in[4];
  const float* pre_b = (const float*)d_in[5];
  const float* pre_g = (const float*)d_in[6];
  const float* pre_beta = (const float*)d_in[7];
  const float* pre_a = (const float*)d_in[8];
  const float* blk_Wl = (const float*)d_in[9];
  const float* blk_bl = (const float*)d_in[10];
  const float* blk_Wr = (const float*)d_in[11];
  const float* blk_br = (const float*)d_in[12];
  const float* blk_We = (const float*)d_in[13];
  const float* blk_att = (const float*)d_in[14];
  // d_in[15] = blk_cb: per-channel constant, cancels in the following BN
  const float* blk_bng = (const float*)d_in[16];
  const float* blk_bnb = (const float*)d_in[17];
  const float* blk_pa = (const float*)d_in[18];
  const float* post_W1 = (const float*)d_in[19];
  const float* post_b1 = (const float*)d_in[20];
  const float* post_g = (const float*)d_in[21];
  const float* post_beta = (const float*)d_in[22];
  const float* post_a = (const float*)d_in[23];
  const float* post_W2 = (const float*)d_in[24];
  const float* post_b2 = (const float*)d_in[25];

  const int gGemm = (kN + 63) / 64;

  GCN_41781441855659_kernel<<<65, 256, 0, stream>>>();

  // ---- pre layer: XL = x@W^T+b; F0 = prelu(bn(XL)) ----
  k_gemm_dual<<<gGemm, 256, 0, stream>>>(0, x, pre_W, pre_b, pre_W, pre_b);
  k_bn_stats<<<256, 256, 0, stream>>>(1);
  k_bn_apply<<<2048, 256, 0, stream>>>(1, 0, 1, pre_g, pre_beta, pre_a);

  // ---- 3 blocks x 2 GATv2 convs ----
  for (int l = 0; l < 6; l++) {
    int j = l & 1;
    const float* Wl = blk_Wl + (size_t)l * kH * kH;
    const float* bl = blk_bl + (size_t)l * kH;
    const float* Wr = blk_Wr + (size_t)l * kH * kH;
    const float* br = blk_br + (size_t)l * kH;
    const float* We = blk_We + (size_t)l * kH * 2;
    const float* att = blk_att + (size_t)l * kH;
    const float* bng = blk_bng + (size_t)l * kH;
    const float* bnb = blk_bnb + (size_t)l * kH;
    const float* pa = blk_pa + l;

    k_zero_conv<<<256, 256, 0, stream>>>();
    k_zero_acc<<<2048, 256, 0, stream>>>();
    k_gemm_dual<<<gGemm, 256, 0, stream>>>((j == 0) ? 1 : 2, x, Wl, bl, Wr,
                                           br);
    k_edge_logits<<<kE / 4, 256, 0, stream>>>(src, dst, ea, We, att);
    k_edge_softmax<<<kE / 256, 256, 0, stream>>>(dst);
    k_edge_aggr<<<kE / 4, 256, 0, stream>>>(src, dst);
    k_bn_stats<<<256, 256, 0, stream>>>(2);
    if (j == 0) {
      // F1 = prelu(bn(ACC))
      k_bn_apply<<<2048, 256, 0, stream>>>(2, 0, 2, bng, bnb, pa);
    } else {
      // F0 = prelu(F0 + bn(ACC))
      k_bn_apply<<<2048, 256, 0, stream>>>(2, 1, 1, bng, bnb, pa);
    }
  }

  // ---- pooling (256 segments) + head ----
  k_pool_max<<<(kN + 3) / 4, 256, 0, stream>>>(batch);
  k_head_gemm1<<<kG, 256, 0, stream>>>(post_W1, post_b1);
  k_head_out<<<kG, 256, 0, stream>>>(post_g, post_beta, post_a, post_W2,
                                     post_b2, (float*)d_out);
}

// Round 7
// 1533.631 us; speedup vs baseline: 2.0415x; 2.0415x over previous
//
#include <hip/hip_runtime.h>

static constexpr int kN = 50000;    // nodes
static constexpr int kE = 800000;   // edges
static constexpr int kH = 64;       // hidden
static constexpr int kG = 256;      // graphs (pool segments)
static constexpr int kC = 250;      // classes
static constexpr int kNH = kN * kH;
static constexpr float kEps = 1e-5f;
static constexpr float kNeg = 0.2f;
static constexpr float kNegInf = -3.402823466e38f;

// ---- device-global scratch (rewritten every call) ----
__device__ float g_F0[kNH];
__device__ float g_F1[kNH];
__device__ float g_XL[kNH];
__device__ float g_XR[kNH];
__device__ float g_ACC[kNH];
__device__ int g_DEG[kN];
__device__ int g_CUR[kN];
__device__ int g_ROW[kN + 1];
__device__ int g_CSRC[kE];
__device__ float2 g_CEA[kE];
__device__ float g_SUMS2[7 * 128];     // 7 BN instances x (64 sum + 64 sumsq)
__device__ unsigned g_POOL[kG * kH];   // 16384
__device__ float g_Z[kG * 256];        // 65536
__device__ float g_HSUMS[512];         // head BN stats

// ---- monotonic float<->uint encoding for atomicMax on floats ----
__device__ inline unsigned fenc(float f) {
  unsigned u = __float_as_uint(f);
  return (u & 0x80000000u) ? ~u : (u | 0x80000000u);
}
__device__ inline float fdec(unsigned u) {
  return (u & 0x80000000u) ? __uint_as_float(u & 0x7FFFFFFFu)
                           : __uint_as_float(~u);
}

// ---- start-of-call zeroing ----
__global__ void GCN_41781441855659_kernel() {
  int i = blockIdx.x * 256 + threadIdx.x;
  int stride = gridDim.x * 256;
  for (int k = i; k < kN; k += stride) {
    g_DEG[k] = 0;
    g_CUR[k] = 0;
  }
  for (int k = i; k < kG * kH; k += stride) g_POOL[k] = 0u;
  for (int k = i; k < 7 * 128; k += stride) g_SUMS2[k] = 0.0f;
  for (int k = i; k < 512; k += stride) g_HSUMS[k] = 0.0f;
}

// ---- CSR build 1: in-degree histogram ----
__global__ void k_deg_count(const int* dst) {
  int e = blockIdx.x * 256 + threadIdx.x;
  if (e < kE) atomicAdd(&g_DEG[dst[e]], 1);
}

// ---- CSR build 2: exclusive prefix scan over kN (single block, 1024 thr) ----
__global__ void k_scan() {
  __shared__ int s[1024];
  int tid = threadIdx.x;
  int running = 0;
  for (int base = 0; base < kN; base += 1024) {
    int idx = base + tid;
    int v = (idx < kN) ? g_DEG[idx] : 0;
    s[tid] = v;
    __syncthreads();
    for (int off = 1; off < 1024; off <<= 1) {
      int t = (tid >= off) ? s[tid - off] : 0;
      __syncthreads();
      s[tid] += t;
      __syncthreads();
    }
    if (idx < kN) g_ROW[idx] = running + s[tid] - v;  // exclusive
    int total = s[1023];
    __syncthreads();
    running += total;
  }
  if (tid == 0) g_ROW[kN] = running;
}

// ---- CSR build 3: scatter src + edge_attr into CSR order ----
__global__ void k_csr_scatter(const int* src, const int* dst,
                              const float* ea) {
  int e = blockIdx.x * 256 + threadIdx.x;
  if (e >= kE) return;
  int d = dst[e];
  int slot = g_ROW[d] + atomicAdd(&g_CUR[d], 1);
  g_CSRC[slot] = src[e];
  g_CEA[slot] = make_float2(ea[e * 2 + 0], ea[e * 2 + 1]);
}

// ---- dual GEMM: g_XL = X*Wl^T + bl ; g_XR = X*Wr^T + br ----
// sel: 0 -> Xext, 1 -> g_F0, 2 -> g_F1.
__global__ void k_gemm_dual(int sel, const float* Xext, const float* Wl,
                            const float* bl, const float* Wr,
                            const float* br) {
  const float* X = (sel == 0) ? Xext : (sel == 1 ? g_F0 : g_F1);
  __shared__ float wl[64][64];
  __shared__ float wr[64][64];
  for (int i = threadIdx.x; i < 4096; i += 256) {
    int c = i >> 6, k = i & 63;
    wl[k][c] = Wl[i];  // transposed store
    wr[k][c] = Wr[i];
  }
  __syncthreads();
  int lane = threadIdx.x & 63;
  int w = threadIdx.x >> 6;
  int r0 = blockIdx.x * 64;
  for (int rl = w; rl < 64; rl += 4) {
    int r = r0 + rl;
    if (r >= kN) break;
    const float* xrow = X + (size_t)r * kH;
    float accl = bl[lane];
    float accr = br[lane];
#pragma unroll
    for (int k = 0; k < 64; k++) {
      float xv = xrow[k];
      accl += xv * wl[k][lane];
      accr += xv * wr[k][lane];
    }
    g_XL[(size_t)r * 64 + lane] = accl;
    g_XR[(size_t)r * 64 + lane] = accr;
  }
}

// ---- fused GATv2 edge stage: wave per node, online softmax, no atomics ----
__global__ void k_gat_fused(const float* We, const float* att) {
  int d = blockIdx.x * 4 + (threadIdx.x >> 6);
  int lane = threadIdx.x & 63;
  if (d >= kN) return;
  float we0 = We[lane * 2 + 0], we1 = We[lane * 2 + 1];
  float av = att[lane];
  float xr = g_XR[(size_t)d * 64 + lane];
  int beg = g_ROW[d], end = g_ROW[d + 1];
  float m = kNegInf, den = 0.0f, acc = 0.0f;
  for (int i = beg; i < end; i++) {
    int s = g_CSRC[i];
    float2 eav = g_CEA[i];
    float xl = g_XL[(size_t)s * 64 + lane];
    float me = xl + xr + eav.x * we0 + eav.y * we1;
    me = (me >= 0.0f) ? me : kNeg * me;
    float t = me * av;
#pragma unroll
    for (int off = 32; off; off >>= 1) t += __shfl_xor(t, off);
    // online softmax update (t identical across lanes)
    float mnew = fmaxf(m, t);
    float scale = expf(m - mnew);  // exp(-inf)=0 on first edge
    float w = expf(t - mnew);
    den = den * scale + w;
    acc = acc * scale + w * xl;
    m = mnew;
  }
  g_ACC[(size_t)d * 64 + lane] = (den > 0.0f) ? acc / den : 0.0f;
}

// ---- BN stats: per-channel sum & sumsq. sel: 1 -> g_XL, 2 -> g_ACC ----
__global__ void k_bn_stats(int layer, int sel) {
  const float* x = (sel == 1) ? g_XL : g_ACC;
  float* SUMS = g_SUMS2 + layer * 128;
  int c = threadIdx.x & 63;
  int sub = threadIdx.x >> 6;
  float s = 0.0f, ss = 0.0f;
  for (int r = blockIdx.x * 4 + sub; r < kN; r += gridDim.x * 4) {
    float v = x[(size_t)r * 64 + c];
    s += v;
    ss += v * v;
  }
  __shared__ float ls[4][64];
  __shared__ float lss[4][64];
  ls[sub][c] = s;
  lss[sub][c] = ss;
  __syncthreads();
  if (threadIdx.x < 64) {
    float t = ls[0][c] + ls[1][c] + ls[2][c] + ls[3][c];
    float tt = lss[0][c] + lss[1][c] + lss[2][c] + lss[3][c];
    atomicAdd(&SUMS[c], t);
    atomicAdd(&SUMS[64 + c], tt);
  }
}

// ---- BN apply + optional residual + PReLU ----
__global__ void k_bn_apply(int layer, int sel_in, int use_res, int sel_out,
                           const float* g, const float* beta,
                           const float* pa) {
  const float* x = (sel_in == 1) ? g_XL : g_ACC;
  float* out = (sel_out == 1) ? g_F0 : g_F1;
  const float* SUMS = g_SUMS2 + layer * 128;
  const float inv = 1.0f / (float)kN;
  float a = pa[0];
  for (int idx = blockIdx.x * 256 + threadIdx.x; idx < kNH;
       idx += gridDim.x * 256) {
    int c = idx & 63;
    float mean = SUMS[c] * inv;
    float var = SUMS[64 + c] * inv - mean * mean;
    float sc = g[c] * rsqrtf(var + kEps);
    float sh = beta[c] - mean * sc;
    float v = x[idx] * sc + sh;
    if (use_res) v += g_F0[idx];
    out[idx] = (v >= 0.0f) ? v : a * v;
  }
}

// ---- segment max pool: wave per row, atomicMax into POOL ----
__global__ void k_pool_max(const int* batch) {
  int r = blockIdx.x * 4 + (threadIdx.x >> 6);
  int lane = threadIdx.x & 63;
  if (r >= kN) return;
  int g = batch[r];
  float v = g_F0[(size_t)r * 64 + lane];
  atomicMax(&g_POOL[g * 64 + lane], fenc(v));
}

// ---- head stage 1: Z[g][j] = b1[j] + pooled[g].W1[j]; BN stats over G ----
__global__ void k_head_gemm1(const float* W1, const float* b1) {
  int g = blockIdx.x;
  int j = threadIdx.x;
  __shared__ float p[64];
  if (j < 64) p[j] = fdec(g_POOL[g * 64 + j]);
  __syncthreads();
  float y = b1[j];
  const float* wrow = W1 + (size_t)j * 64;
#pragma unroll
  for (int k = 0; k < 64; k++) y += p[k] * wrow[k];
  g_Z[(size_t)g * 256 + j] = y;
  atomicAdd(&g_HSUMS[j], y);
  atomicAdd(&g_HSUMS[256 + j], y * y);
}

// ---- head stage 2: BN -> PReLU -> out = z @ W2^T + b2 ----
__global__ void k_head_out(const float* g1, const float* beta1,
                           const float* pa, const float* W2, const float* b2,
                           float* out) {
  int g = blockIdx.x;
  int j = threadIdx.x;
  __shared__ float zs[256];
  {
    const float inv = 1.0f / (float)kG;
    float mean = g_HSUMS[j] * inv;
    float var = g_HSUMS[256 + j] * inv - mean * mean;
    float sc = g1[j] * rsqrtf(var + kEps);
    float a = pa[0];
    float z = (g_Z[(size_t)g * 256 + j] - mean) * sc + beta1[j];
    zs[j] = (z >= 0.0f) ? z : a * z;
  }
  __syncthreads();
  if (j < kC) {
    const float* wrow = W2 + (size_t)j * 256;
    float acc = b2[j];
#pragma unroll 8
    for (int k = 0; k < 256; k++) acc += zs[k] * wrow[k];
    out[(size_t)g * kC + j] = acc;
  }
}

extern "C" void kernel_launch(void* const* d_in, const int* in_sizes, int n_in,
                              void* d_out, int out_size, void* d_ws,
                              size_t ws_size, hipStream_t stream) {
  const float* x = (const float*)d_in[0];
  const int* ei = (const int*)d_in[1];
  const int* src = ei;
  const int* dst = ei + kE;
  const float* ea = (const float*)d_in[2];
  const int* batch = (const int*)d_in[3];
  const float* pre_W = (const float*)d_in[4];
  const float* pre_b = (const float*)d_in[5];
  const float* pre_g = (const float*)d_in[6];
  const float* pre_beta = (const float*)d_in[7];
  const float* pre_a = (const float*)d_in[8];
  const float* blk_Wl = (const float*)d_in[9];
  const float* blk_bl = (const float*)d_in[10];
  const float* blk_Wr = (const float*)d_in[11];
  const float* blk_br = (const float*)d_in[12];
  const float* blk_We = (const float*)d_in[13];
  const float* blk_att = (const float*)d_in[14];
  // d_in[15] = blk_cb: per-channel constant, cancels in the following BN
  const float* blk_bng = (const float*)d_in[16];
  const float* blk_bnb = (const float*)d_in[17];
  const float* blk_pa = (const float*)d_in[18];
  const float* post_W1 = (const float*)d_in[19];
  const float* post_b1 = (const float*)d_in[20];
  const float* post_g = (const float*)d_in[21];
  const float* post_beta = (const float*)d_in[22];
  const float* post_a = (const float*)d_in[23];
  const float* post_W2 = (const float*)d_in[24];
  const float* post_b2 = (const float*)d_in[25];

  const int gGemm = (kN + 63) / 64;
  const int gEdge = (kE + 255) / 256;
  const int gNode4 = (kN + 3) / 4;

  // ---- init + CSR build (once per call) ----
  GCN_41781441855659_kernel<<<256, 256, 0, stream>>>();
  k_deg_count<<<gEdge, 256, 0, stream>>>(dst);
  k_scan<<<1, 1024, 0, stream>>>();
  k_csr_scatter<<<gEdge, 256, 0, stream>>>(src, dst, ea);

  // ---- pre layer: XL = x@W^T+b; F0 = prelu(bn(XL)) ----
  k_gemm_dual<<<gGemm, 256, 0, stream>>>(0, x, pre_W, pre_b, pre_W, pre_b);
  k_bn_stats<<<256, 256, 0, stream>>>(0, 1);
  k_bn_apply<<<2048, 256, 0, stream>>>(0, 1, 0, 1, pre_g, pre_beta, pre_a);

  // ---- 3 blocks x 2 GATv2 convs ----
  for (int l = 0; l < 6; l++) {
    int j = l & 1;
    const float* Wl = blk_Wl + (size_t)l * kH * kH;
    const float* bl = blk_bl + (size_t)l * kH;
    const float* Wr = blk_Wr + (size_t)l * kH * kH;
    const float* br = blk_br + (size_t)l * kH;
    const float* We = blk_We + (size_t)l * kH * 2;
    const float* att = blk_att + (size_t)l * kH;
    const float* bng = blk_bng + (size_t)l * kH;
    const float* bnb = blk_bnb + (size_t)l * kH;
    const float* pa = blk_pa + l;

    k_gemm_dual<<<gGemm, 256, 0, stream>>>((j == 0) ? 1 : 2, x, Wl, bl, Wr,
                                           br);
    k_gat_fused<<<gNode4, 256, 0, stream>>>(We, att);
    k_bn_stats<<<256, 256, 0, stream>>>(1 + l, 2);
    if (j == 0) {
      // F1 = prelu(bn(ACC))
      k_bn_apply<<<2048, 256, 0, stream>>>(1 + l, 2, 0, 2, bng, bnb, pa);
    } else {
      // F0 = prelu(F0 + bn(ACC))
      k_bn_apply<<<2048, 256, 0, stream>>>(1 + l, 2, 1, 1, bng, bnb, pa);
    }
  }

  // ---- pooling (256 segments) + head ----
  k_pool_max<<<gNode4, 256, 0, stream>>>(batch);
  k_head_gemm1<<<kG, 256, 0, stream>>>(post_W1, post_b1);
  k_head_out<<<kG, 256, 0, stream>>>(post_g, post_beta, post_a, post_W2,
                                     post_b2, (float*)d_out);
}

// Round 8
// 1064.638 us; speedup vs baseline: 2.9408x; 1.4405x over previous
//
#include <hip/hip_runtime.h>

static constexpr int kN = 50000;    // nodes
static constexpr int kE = 800000;   // edges
static constexpr int kH = 64;       // hidden
static constexpr int kG = 256;      // graphs (pool segments)
static constexpr int kC = 250;      // classes
static constexpr int kNH = kN * kH;
static constexpr float kEps = 1e-5f;
static constexpr float kNeg = 0.2f;
static constexpr float kNegInf = -3.402823466e38f;  // -FLT_MAX (finite!)
static constexpr int kScanB = (kN + 1023) / 1024;   // 49

// ---- device-global scratch (rewritten every call) ----
__device__ float g_F0[kNH];
__device__ float g_F1[kNH];
__device__ float g_XL[kNH];
__device__ float g_XR[kNH];
__device__ float g_ACC[kNH];
__device__ int g_DEG[kN];
__device__ int g_CUR[kN];
__device__ int g_ROW[kN + 1];
__device__ int g_BTOT[64];
__device__ int g_BOFF[64];
__device__ int g_CSRC[kE];
__device__ float2 g_CEA[kE];
__device__ float g_SUMS2[7 * 128];     // 7 BN instances x (64 sum + 64 sumsq)
__device__ unsigned g_POOL[kG * kH];
__device__ float g_Z[kG * 256];
__device__ float g_HSUMS[512];

// ---- monotonic float<->uint encoding for atomicMax on floats ----
__device__ inline unsigned fenc(float f) {
  unsigned u = __float_as_uint(f);
  return (u & 0x80000000u) ? ~u : (u | 0x80000000u);
}
__device__ inline float fdec(unsigned u) {
  return (u & 0x80000000u) ? __uint_as_float(u & 0x7FFFFFFFu)
                           : __uint_as_float(~u);
}

// ---- start-of-call zeroing ----
__global__ void GCN_41781441855659_kernel() {
  int i = blockIdx.x * 256 + threadIdx.x;
  int stride = gridDim.x * 256;
  for (int k = i; k < kN; k += stride) {
    g_DEG[k] = 0;
    g_CUR[k] = 0;
  }
  for (int k = i; k < kG * kH; k += stride) g_POOL[k] = 0u;
  for (int k = i; k < 7 * 128; k += stride) g_SUMS2[k] = 0.0f;
  for (int k = i; k < 512; k += stride) g_HSUMS[k] = 0.0f;
}

// ---- CSR build 1: in-degree histogram ----
__global__ void k_deg_count(const int* dst) {
  int e = blockIdx.x * 256 + threadIdx.x;
  if (e < kE) atomicAdd(&g_DEG[dst[e]], 1);
}

// ---- CSR build 2a: per-chunk exclusive scan (49 blocks x 1024) ----
__global__ void k_scan1() {
  __shared__ int s[1024];
  int b = blockIdx.x, tid = threadIdx.x;
  int idx = b * 1024 + tid;
  int v = (idx < kN) ? g_DEG[idx] : 0;
  s[tid] = v;
  __syncthreads();
  for (int off = 1; off < 1024; off <<= 1) {
    int t = (tid >= off) ? s[tid - off] : 0;
    __syncthreads();
    s[tid] += t;
    __syncthreads();
  }
  if (idx < kN) g_ROW[idx] = s[tid] - v;  // chunk-exclusive
  if (tid == 1023) g_BTOT[b] = s[1023];
}

// ---- CSR build 2b: scan chunk totals (tiny) ----
__global__ void k_scan2() {
  if (threadIdx.x == 0) {
    int run = 0;
    for (int b = 0; b < kScanB; b++) {
      g_BOFF[b] = run;
      run += g_BTOT[b];
    }
    g_ROW[kN] = run;
  }
}

// ---- CSR build 2c: add chunk offsets ----
__global__ void k_scan3() {
  int b = blockIdx.x;
  int idx = b * 1024 + threadIdx.x;
  if (idx < kN) g_ROW[idx] += g_BOFF[b];
}

// ---- CSR build 3: scatter src + edge_attr into CSR order ----
__global__ void k_csr_scatter(const int* src, const int* dst,
                              const float* ea) {
  int e = blockIdx.x * 256 + threadIdx.x;
  if (e >= kE) return;
  int d = dst[e];
  int slot = g_ROW[d] + atomicAdd(&g_CUR[d], 1);
  g_CSRC[slot] = src[e];
  g_CEA[slot] = make_float2(ea[e * 2 + 0], ea[e * 2 + 1]);
}

// ---- dual GEMM: g_XL = X*Wl^T + bl ; g_XR = X*Wr^T + br ----
__global__ void k_gemm_dual(int sel, const float* Xext, const float* Wl,
                            const float* bl, const float* Wr,
                            const float* br) {
  const float* X = (sel == 0) ? Xext : (sel == 1 ? g_F0 : g_F1);
  __shared__ float wl[64][64];
  __shared__ float wr[64][64];
  for (int i = threadIdx.x; i < 4096; i += 256) {
    int c = i >> 6, k = i & 63;
    wl[k][c] = Wl[i];  // transposed store
    wr[k][c] = Wr[i];
  }
  __syncthreads();
  int lane = threadIdx.x & 63;
  int w = threadIdx.x >> 6;
  int r0 = blockIdx.x * 64;
  for (int rl = w; rl < 64; rl += 4) {
    int r = r0 + rl;
    if (r >= kN) break;
    const float* xrow = X + (size_t)r * kH;
    float accl = bl[lane];
    float accr = br[lane];
#pragma unroll
    for (int k = 0; k < 64; k++) {
      float xv = xrow[k];
      accl += xv * wl[k][lane];
      accr += xv * wr[k][lane];
    }
    g_XL[(size_t)r * 64 + lane] = accl;
    g_XR[(size_t)r * 64 + lane] = accr;
  }
}

// ---- fused GATv2 edge stage: wave per node, 4 groups x 16 lanes x 4ch ----
__global__ void k_gat_fused(const float* We, const float* att) {
  int wid = threadIdx.x >> 6;
  int d = blockIdx.x * 4 + wid;
  if (d >= kN) return;
  int lane = threadIdx.x & 63;
  int grp = lane >> 4;   // 0..3: edge slot
  int q = lane & 15;     // 0..15: channel quad
  int c0 = q * 4;
  int beg = g_ROW[d], end = g_ROW[d + 1];
  float4 outv = make_float4(0.0f, 0.0f, 0.0f, 0.0f);
  if (beg < end) {
    const float4 xr = *(const float4*)&g_XR[(size_t)d * 64 + c0];
    const float4 wea = *(const float4*)&We[c0 * 2];      // (w0,w1) c0,c0+1
    const float4 web = *(const float4*)&We[c0 * 2 + 4];  // (w0,w1) c0+2,c0+3
    const float4 at4 = *(const float4*)&att[c0];
    float m = kNegInf, den = 0.0f;
    float4 acc = make_float4(0.0f, 0.0f, 0.0f, 0.0f);
    for (int i = beg + grp; i < end; i += 4) {
      int s = g_CSRC[i];
      float2 eav = g_CEA[i];
      const float4 xl = *(const float4*)&g_XL[(size_t)s * 64 + c0];
      float me0 = xl.x + xr.x + eav.x * wea.x + eav.y * wea.y;
      float me1 = xl.y + xr.y + eav.x * wea.z + eav.y * wea.w;
      float me2 = xl.z + xr.z + eav.x * web.x + eav.y * web.y;
      float me3 = xl.w + xr.w + eav.x * web.z + eav.y * web.w;
      me0 = (me0 >= 0.0f) ? me0 : kNeg * me0;
      me1 = (me1 >= 0.0f) ? me1 : kNeg * me1;
      me2 = (me2 >= 0.0f) ? me2 : kNeg * me2;
      me3 = (me3 >= 0.0f) ? me3 : kNeg * me3;
      float part =
          me0 * at4.x + me1 * at4.y + me2 * at4.z + me3 * at4.w;
      part += __shfl_xor(part, 1);
      part += __shfl_xor(part, 2);
      part += __shfl_xor(part, 4);
      part += __shfl_xor(part, 8);
      // online softmax, exactly one exp per edge (branch is group-uniform)
      if (part <= m) {
        float w = __expf(part - m);
        den += w;
        acc.x += w * xl.x;
        acc.y += w * xl.y;
        acc.z += w * xl.z;
        acc.w += w * xl.w;
      } else {
        float sc = __expf(m - part);
        den = den * sc + 1.0f;
        acc.x = acc.x * sc + xl.x;
        acc.y = acc.y * sc + xl.y;
        acc.z = acc.z * sc + xl.z;
        acc.w = acc.w * sc + xl.w;
        m = part;
      }
    }
    // merge the 4 groups' online-softmax states (all finite; empty -> 0)
#pragma unroll
    for (int off = 16; off <= 32; off <<= 1) {
      float mo = __shfl_xor(m, off);
      float deno = __shfl_xor(den, off);
      float ax = __shfl_xor(acc.x, off);
      float ay = __shfl_xor(acc.y, off);
      float az = __shfl_xor(acc.z, off);
      float aw = __shfl_xor(acc.w, off);
      float mn = fmaxf(m, mo);
      float sa = __expf(m - mn);
      float sb = __expf(mo - mn);
      den = den * sa + deno * sb;
      acc.x = acc.x * sa + ax * sb;
      acc.y = acc.y * sa + ay * sb;
      acc.z = acc.z * sa + az * sb;
      acc.w = acc.w * sa + aw * sb;
      m = mn;
    }
    float inv = 1.0f / den;
    outv = make_float4(acc.x * inv, acc.y * inv, acc.z * inv, acc.w * inv);
  }
  if (grp == 0) *(float4*)&g_ACC[(size_t)d * 64 + c0] = outv;
}

// ---- BN stats: per-channel sum & sumsq. sel: 1 -> g_XL, 2 -> g_ACC ----
__global__ void k_bn_stats(int layer, int sel) {
  const float* x = (sel == 1) ? g_XL : g_ACC;
  float* SUMS = g_SUMS2 + layer * 128;
  int c = threadIdx.x & 63;
  int sub = threadIdx.x >> 6;
  float s = 0.0f, ss = 0.0f;
  for (int r = blockIdx.x * 4 + sub; r < kN; r += gridDim.x * 4) {
    float v = x[(size_t)r * 64 + c];
    s += v;
    ss += v * v;
  }
  __shared__ float ls[4][64];
  __shared__ float lss[4][64];
  ls[sub][c] = s;
  lss[sub][c] = ss;
  __syncthreads();
  if (threadIdx.x < 64) {
    float t = ls[0][c] + ls[1][c] + ls[2][c] + ls[3][c];
    float tt = lss[0][c] + lss[1][c] + lss[2][c] + lss[3][c];
    atomicAdd(&SUMS[c], t);
    atomicAdd(&SUMS[64 + c], tt);
  }
}

// ---- BN apply + optional residual + PReLU ----
__global__ void k_bn_apply(int layer, int sel_in, int use_res, int sel_out,
                           const float* g, const float* beta,
                           const float* pa) {
  const float* x = (sel_in == 1) ? g_XL : g_ACC;
  float* out = (sel_out == 1) ? g_F0 : g_F1;
  const float* SUMS = g_SUMS2 + layer * 128;
  const float inv = 1.0f / (float)kN;
  float a = pa[0];
  for (int idx = blockIdx.x * 256 + threadIdx.x; idx < kNH;
       idx += gridDim.x * 256) {
    int c = idx & 63;
    float mean = SUMS[c] * inv;
    float var = SUMS[64 + c] * inv - mean * mean;
    float sc = g[c] * rsqrtf(var + kEps);
    float sh = beta[c] - mean * sc;
    float v = x[idx] * sc + sh;
    if (use_res) v += g_F0[idx];
    out[idx] = (v >= 0.0f) ? v : a * v;
  }
}

// ---- segment max pool: wave per row, atomicMax into POOL ----
__global__ void k_pool_max(const int* batch) {
  int r = blockIdx.x * 4 + (threadIdx.x >> 6);
  int lane = threadIdx.x & 63;
  if (r >= kN) return;
  int g = batch[r];
  float v = g_F0[(size_t)r * 64 + lane];
  atomicMax(&g_POOL[g * 64 + lane], fenc(v));
}

// ---- head stage 1: Z[g][j] = b1[j] + pooled[g].W1[j]; BN stats over G ----
__global__ void k_head_gemm1(const float* W1, const float* b1) {
  int g = blockIdx.x;
  int j = threadIdx.x;
  __shared__ float p[64];
  if (j < 64) p[j] = fdec(g_POOL[g * 64 + j]);
  __syncthreads();
  float y = b1[j];
  const float* wrow = W1 + (size_t)j * 64;
#pragma unroll
  for (int k = 0; k < 64; k++) y += p[k] * wrow[k];
  g_Z[(size_t)g * 256 + j] = y;
  atomicAdd(&g_HSUMS[j], y);
  atomicAdd(&g_HSUMS[256 + j], y * y);
}

// ---- head stage 2: BN -> PReLU -> out = z @ W2^T + b2 ----
__global__ void k_head_out(const float* g1, const float* beta1,
                           const float* pa, const float* W2, const float* b2,
                           float* out) {
  int g = blockIdx.x;
  int j = threadIdx.x;
  __shared__ float zs[256];
  {
    const float inv = 1.0f / (float)kG;
    float mean = g_HSUMS[j] * inv;
    float var = g_HSUMS[256 + j] * inv - mean * mean;
    float sc = g1[j] * rsqrtf(var + kEps);
    float a = pa[0];
    float z = (g_Z[(size_t)g * 256 + j] - mean) * sc + beta1[j];
    zs[j] = (z >= 0.0f) ? z : a * z;
  }
  __syncthreads();
  if (j < kC) {
    const float* wrow = W2 + (size_t)j * 256;
    float acc = b2[j];
#pragma unroll 8
    for (int k = 0; k < 256; k++) acc += zs[k] * wrow[k];
    out[(size_t)g * kC + j] = acc;
  }
}

extern "C" void kernel_launch(void* const* d_in, const int* in_sizes, int n_in,
                              void* d_out, int out_size, void* d_ws,
                              size_t ws_size, hipStream_t stream) {
  const float* x = (const float*)d_in[0];
  const int* ei = (const int*)d_in[1];
  const int* src = ei;
  const int* dst = ei + kE;
  const float* ea = (const float*)d_in[2];
  const int* batch = (const int*)d_in[3];
  const float* pre_W = (const float*)d_in[4];
  const float* pre_b = (const float*)d_in[5];
  const float* pre_g = (const float*)d_in[6];
  const float* pre_beta = (const float*)d_in[7];
  const float* pre_a = (const float*)d_in[8];
  const float* blk_Wl = (const float*)d_in[9];
  const float* blk_bl = (const float*)d_in[10];
  const float* blk_Wr = (const float*)d_in[11];
  const float* blk_br = (const float*)d_in[12];
  const float* blk_We = (const float*)d_in[13];
  const float* blk_att = (const float*)d_in[14];
  // d_in[15] = blk_cb: per-channel constant, cancels in the following BN
  const float* blk_bng = (const float*)d_in[16];
  const float* blk_bnb = (const float*)d_in[17];
  const float* blk_pa = (const float*)d_in[18];
  const float* post_W1 = (const float*)d_in[19];
  const float* post_b1 = (const float*)d_in[20];
  const float* post_g = (const float*)d_in[21];
  const float* post_beta = (const float*)d_in[22];
  const float* post_a = (const float*)d_in[23];
  const float* post_W2 = (const float*)d_in[24];
  const float* post_b2 = (const float*)d_in[25];

  const int gGemm = (kN + 63) / 64;
  const int gEdge = (kE + 255) / 256;
  const int gNode4 = (kN + 3) / 4;

  // ---- init + CSR build (once per call) ----
  GCN_41781441855659_kernel<<<256, 256, 0, stream>>>();
  k_deg_count<<<gEdge, 256, 0, stream>>>(dst);
  k_scan1<<<kScanB, 1024, 0, stream>>>();
  k_scan2<<<1, 64, 0, stream>>>();
  k_scan3<<<kScanB, 1024, 0, stream>>>();
  k_csr_scatter<<<gEdge, 256, 0, stream>>>(src, dst, ea);

  // ---- pre layer: XL = x@W^T+b; F0 = prelu(bn(XL)) ----
  k_gemm_dual<<<gGemm, 256, 0, stream>>>(0, x, pre_W, pre_b, pre_W, pre_b);
  k_bn_stats<<<256, 256, 0, stream>>>(0, 1);
  k_bn_apply<<<2048, 256, 0, stream>>>(0, 1, 0, 1, pre_g, pre_beta, pre_a);

  // ---- 3 blocks x 2 GATv2 convs ----
  for (int l = 0; l < 6; l++) {
    int j = l & 1;
    const float* Wl = blk_Wl + (size_t)l * kH * kH;
    const float* bl = blk_bl + (size_t)l * kH;
    const float* Wr = blk_Wr + (size_t)l * kH * kH;
    const float* br = blk_br + (size_t)l * kH;
    const float* We = blk_We + (size_t)l * kH * 2;
    const float* att = blk_att + (size_t)l * kH;
    const float* bng = blk_bng + (size_t)l * kH;
    const float* bnb = blk_bnb + (size_t)l * kH;
    const float* pa = blk_pa + l;

    k_gemm_dual<<<gGemm, 256, 0, stream>>>((j == 0) ? 1 : 2, x, Wl, bl, Wr,
                                           br);
    k_gat_fused<<<gNode4, 256, 0, stream>>>(We, att);
    k_bn_stats<<<256, 256, 0, stream>>>(1 + l, 2);
    if (j == 0) {
      k_bn_apply<<<2048, 256, 0, stream>>>(1 + l, 2, 0, 2, bng, bnb, pa);
    } else {
      k_bn_apply<<<2048, 256, 0, stream>>>(1 + l, 2, 1, 1, bng, bnb, pa);
    }
  }

  // ---- pooling (256 segments) + head ----
  k_pool_max<<<gNode4, 256, 0, stream>>>(batch);
  k_head_gemm1<<<kG, 256, 0, stream>>>(post_W1, post_b1);
  k_head_out<<<kG, 256, 0, stream>>>(post_g, post_beta, post_a, post_W2,
                                     post_b2, (float*)d_out);
}